// Round 13
// baseline (321.595 us; speedup 1.0000x reference)
//
#include <hip/hip_runtime.h>

typedef __attribute__((ext_vector_type(8))) _Float16 half8;
typedef __attribute__((ext_vector_type(4))) _Float16 half4;
typedef __attribute__((ext_vector_type(2))) _Float16 half2_t;
typedef __attribute__((ext_vector_type(2))) __fp16 fp16x2;
typedef __attribute__((ext_vector_type(4))) float f32x4;

#define AS1 __attribute__((address_space(1)))
#define AS3 __attribute__((address_space(3)))

constexpr int SEQ = 2048, DM = 512, FFD = 2048, NH = 8, DH = 64;
constexpr int M = 2 * SEQ; // 4096 rows
constexpr float QSCALE = 0.125f * 1.4426950408889634f; // 1/sqrt(64) * log2(e)

// ======== fused preprocessing: 10 weight transposes + biases + 2 casts ======
__global__ __launch_bounds__(256)
void preproc(const float* __restrict__ q1_w, const float* __restrict__ k1_w,
             const float* __restrict__ v1_w, const float* __restrict__ o1_w,
             const float* __restrict__ q2_w, const float* __restrict__ k2_w,
             const float* __restrict__ v2_w, const float* __restrict__ o2_w,
             const float* __restrict__ f1_w, const float* __restrict__ f2_w,
             _Float16* __restrict__ qk1t, _Float16* __restrict__ v1t,
             _Float16* __restrict__ o1t, _Float16* __restrict__ qk2t,
             _Float16* __restrict__ v2t, _Float16* __restrict__ o2t,
             _Float16* __restrict__ f1t, _Float16* __restrict__ f2t,
             const float* __restrict__ q1_b, const float* __restrict__ k1_b,
             const float* __restrict__ q2_b, const float* __restrict__ k2_b,
             float* __restrict__ qk1b, float* __restrict__ qk2b,
             const float* __restrict__ inp, const float* __restrict__ enc,
             _Float16* __restrict__ xh, _Float16* __restrict__ eh) {
    __shared__ _Float16 tile[64 * 65];
    const int j = blockIdx.x, tid = threadIdx.x;
    if (j < 1024) {
        const float* src; _Float16* dst; int K, N, n0, k0;
        if (j < 512) {
            int w8 = j >> 6, t = j & 63;
            K = 512; N = 512; n0 = (t & 7) * 64; k0 = (t >> 3) * 64;
            switch (w8) {
                case 0: src = q1_w; dst = qk1t; break;
                case 1: src = k1_w; dst = qk1t + 512 * 512; break;
                case 2: src = v1_w; dst = v1t; break;
                case 3: src = o1_w; dst = o1t; break;
                case 4: src = q2_w; dst = qk2t; break;
                case 5: src = k2_w; dst = qk2t + 512 * 512; break;
                case 6: src = v2_w; dst = v2t; break;
                default: src = o2_w; dst = o2t; break;
            }
        } else if (j < 768) {
            int t = j - 512; K = 512; N = 2048;
            n0 = (t % 32) * 64; k0 = (t / 32) * 64; src = f1_w; dst = f1t;
        } else {
            int t = j - 768; K = 2048; N = 512;
            n0 = (t % 8) * 64; k0 = (t / 8) * 64; src = f2_w; dst = f2t;
        }
        int c = tid & 63, r4 = tid >> 6;
        for (int i = 0; i < 16; i++) {
            int r = r4 * 16 + i;
            tile[r * 65 + c] = (_Float16)src[(size_t)(k0 + r) * N + n0 + c];
        }
        __syncthreads();
        for (int i = 0; i < 16; i++) {
            int r = r4 * 16 + i;
            dst[(size_t)(n0 + r) * K + k0 + c] = tile[c * 65 + r];
        }
    } else if (j == 1024) {
        for (int i = tid; i < 512; i += 256) { qk1b[i] = q1_b[i]; qk1b[512 + i] = k1_b[i]; }
    } else if (j == 1025) {
        for (int i = tid; i < 512; i += 256) { qk2b[i] = q2_b[i]; qk2b[512 + i] = k2_b[i]; }
    } else {
        int k = j - 1026;                        // 0..2047
        const float* s = (k < 1024) ? inp : enc;
        _Float16* d = (k < 1024) ? xh : eh;
        size_t base = (size_t)(k & 1023) * 2048 + tid * 8;
        f32x4 a = *(const f32x4*)(s + base);
        f32x4 b2 = *(const f32x4*)(s + base + 4);
        half8 h;
        h[0] = (_Float16)a[0]; h[1] = (_Float16)a[1];
        h[2] = (_Float16)a[2]; h[3] = (_Float16)a[3];
        h[4] = (_Float16)b2[0]; h[5] = (_Float16)b2[1];
        h[6] = (_Float16)b2[2]; h[7] = (_Float16)b2[3];
        *(half8*)(d + base) = h;
    }
}

// ---- merged QK-projection (jobs 0..1023) + V1^T GEMM (jobs 1024..1279) ----
__global__ __launch_bounds__(256)
void qkv_gemm(const _Float16* __restrict__ xh, const _Float16* __restrict__ eh,
              const _Float16* __restrict__ qk1t, const _Float16* __restrict__ qk2t,
              const float* __restrict__ qk1b, const float* __restrict__ qk2b,
              _Float16* __restrict__ Qh1, _Float16* __restrict__ Kh1,
              _Float16* __restrict__ Qh2, _Float16* __restrict__ Kh2,
              const _Float16* __restrict__ v1t, const float* __restrict__ v1b,
              _Float16* __restrict__ V1T) {
    __shared__ _Float16 smem[192 * 64];
    const int tid = threadIdx.x;
    const int wid = tid >> 6, lid = tid & 63;
    const int wr = (wid & 1) * 64;
    const int wc = (wid >> 1) * 32;
    const int mi = lid & 15, qd = lid >> 4;
    const int jb = blockIdx.x;
    const _Float16 *Ap, *Bp;
    const float* bias;
    int m0, n0, epi, job = 0;
    if (jb < 1024) {
        epi = 4; job = jb >> 9;
        int L = jb & 511;
        int by = L % 32, bx = L / 32;
        m0 = by * 128; n0 = bx * 64;
        Ap = (job ? eh : xh) + (size_t)m0 * 512;
        Bp = (job ? qk2t : qk1t) + (size_t)n0 * 512;
        bias = job ? qk2b : qk1b;
    } else {
        epi = 3;
        int t = jb - 1024;
        int by = t & 3, bx = t >> 2;
        m0 = by * 128; n0 = bx * 64;
        Ap = v1t + (size_t)m0 * 512;
        Bp = xh + (size_t)n0 * 512;
        bias = v1b;
    }
    const int lrow = lid >> 3;
    const int gblk = (lid & 7) ^ ((lid >> 3) & 7);
    auto stage = [&](int kt) {
        #pragma unroll
        for (int l = 0; l < 4; l++) {
            int c = l * 4 + wid;
            int row = c * 8 + lrow;
            __builtin_amdgcn_global_load_lds(
                (const AS1 unsigned int*)(Ap + (size_t)row * 512 + kt * 64 + gblk * 8),
                (AS3 unsigned int*)&smem[c * 512], 16, 0, 0);
        }
        #pragma unroll
        for (int l = 0; l < 2; l++) {
            int c = l * 4 + wid;
            int row = c * 8 + lrow;
            __builtin_amdgcn_global_load_lds(
                (const AS1 unsigned int*)(Bp + (size_t)row * 512 + kt * 64 + gblk * 8),
                (AS3 unsigned int*)&smem[128 * 64 + c * 512], 16, 0, 0);
        }
    };
    f32x4 acc[4][2] = {};
    stage(0);
    __builtin_amdgcn_s_waitcnt(0x0F70);
    __syncthreads();
    for (int t = 0; t < 8; t++) {
        #pragma unroll
        for (int h = 0; h < 2; h++) {
            const int sA = ((4 * h + qd) ^ (mi & 7)) * 8;
            half8 af[4], bfr[2];
            #pragma unroll
            for (int i = 0; i < 4; i++)
                af[i] = *(const half8*)&smem[(wr + i * 16 + mi) * 64 + sA];
            #pragma unroll
            for (int j = 0; j < 2; j++)
                bfr[j] = *(const half8*)&smem[(128 + wc + j * 16 + mi) * 64 + sA];
            #pragma unroll
            for (int i = 0; i < 4; i++)
                #pragma unroll
                for (int j = 0; j < 2; j++)
                    acc[i][j] = __builtin_amdgcn_mfma_f32_16x16x32_f16(af[i], bfr[j], acc[i][j], 0, 0, 0);
        }
        if (t + 1 < 8) {
            __syncthreads();
            stage(t + 1);
            __builtin_amdgcn_s_waitcnt(0x0F70);
            __syncthreads();
        }
    }
    #pragma unroll
    for (int i = 0; i < 4; i++) {
        #pragma unroll
        for (int j = 0; j < 2; j++) {
            #pragma unroll
            for (int r = 0; r < 4; r++) {
                int row = m0 + wr + i * 16 + qd * 4 + r;
                int col = n0 + wc + j * 16 + mi;
                float v = acc[i][j][r];
                if (epi == 4) {
                    v += bias[col];
                    int hh2 = (col >> 6) & 7, d = col & 63;
                    int bb = row >> 11, nn = row & 2047;
                    size_t idx = (((size_t)bb * 8 + hh2) * SEQ + nn) * 64 + d;
                    if (col < 512) (job ? Qh2 : Qh1)[idx] = (_Float16)(v * QSCALE);
                    else           (job ? Kh2 : Kh1)[idx] = (_Float16)v;
                } else {
                    v += bias[row];                 // per-row bias (V^T output)
                    V1T[(size_t)row * 4096 + col] = (_Float16)v;
                }
            }
        }
    }
}

// -------- GEMM: C = A[M,K] * Bt[N,K]^T + bias, f16 in / f32 acc --------
// EPI 0: plain. EPI 3: transposed-V out (per-ROW bias). EPI 5: split-K slices.
template<int BM, int BN, int WM, int WN, bool RELU, int EPI, int SPLIT>
__global__ __launch_bounds__(256)
void gemm_tn(const _Float16* __restrict__ A, const _Float16* __restrict__ Bt,
             const float* __restrict__ bias,
             float* __restrict__ outF, _Float16* __restrict__ outH,
             int Mtot, int N, int K) {
    constexpr int ROWS = BM + BN;
    __shared__ _Float16 smem[ROWS * 64];
    constexpr int AF = WM / 16, BF = WN / 16;
    constexpr int WROW = BM / WM;
    const int tid = threadIdx.x;
    const int wid = tid >> 6, lid = tid & 63;
    const int wr = (wid % WROW) * WM;
    const int wc = (wid / WROW) * WN;
    const int mi = lid & 15, qd = lid >> 4;
    const int gx = gridDim.x, gy = gridDim.y;
    const int L = blockIdx.y * gx + blockIdx.x;
    const int by = L % gy, bx = L / gy;
    const int m0 = by * BM, n0 = bx * BN;
    const int Kc = K / SPLIT;
    const int kbase = (SPLIT > 1) ? blockIdx.z * Kc : 0;
    const _Float16* Ap = A + (size_t)m0 * K + kbase;
    const _Float16* Bp = Bt + (size_t)n0 * K + kbase;
    const int lrow = lid >> 3;
    const int gblk = (lid & 7) ^ ((lid >> 3) & 7);
    auto stage = [&](int kt) {
        #pragma unroll
        for (int l = 0; l < BM / 32; l++) {
            int c = l * 4 + wid;
            int row = c * 8 + lrow;
            __builtin_amdgcn_global_load_lds(
                (const AS1 unsigned int*)(Ap + (size_t)row * K + kt * 64 + gblk * 8),
                (AS3 unsigned int*)&smem[c * 512], 16, 0, 0);
        }
        #pragma unroll
        for (int l = 0; l < BN / 32; l++) {
            int c = l * 4 + wid;
            int row = c * 8 + lrow;
            __builtin_amdgcn_global_load_lds(
                (const AS1 unsigned int*)(Bp + (size_t)row * K + kt * 64 + gblk * 8),
                (AS3 unsigned int*)&smem[BM * 64 + c * 512], 16, 0, 0);
        }
    };
    f32x4 acc[AF][BF] = {};
    const int NIT = Kc / 64;
    stage(0);
    __builtin_amdgcn_s_waitcnt(0x0F70);
    __syncthreads();
    for (int t = 0; t < NIT; t++) {
        #pragma unroll
        for (int h = 0; h < 2; h++) {
            const int sA = ((4 * h + qd) ^ (mi & 7)) * 8;
            half8 af[AF], bfr[BF];
            #pragma unroll
            for (int i = 0; i < AF; i++)
                af[i] = *(const half8*)&smem[(wr + i * 16 + mi) * 64 + sA];
            #pragma unroll
            for (int j = 0; j < BF; j++)
                bfr[j] = *(const half8*)&smem[(BM + wc + j * 16 + mi) * 64 + sA];
            #pragma unroll
            for (int i = 0; i < AF; i++)
                #pragma unroll
                for (int j = 0; j < BF; j++)
                    acc[i][j] = __builtin_amdgcn_mfma_f32_16x16x32_f16(af[i], bfr[j], acc[i][j], 0, 0, 0);
        }
        if (t + 1 < NIT) {
            __syncthreads();
            stage(t + 1);
            __builtin_amdgcn_s_waitcnt(0x0F70);
            __syncthreads();
        }
    }
    float* oF = outF;
    if (SPLIT > 1 && outF) oF = outF + (size_t)blockIdx.z * Mtot * N;
    _Float16* oH = outH;
    if (EPI == 5) oH = outH + (size_t)blockIdx.z * Mtot * N;
    const bool doBias = bias && (SPLIT == 1 || blockIdx.z == 0);
    #pragma unroll
    for (int i = 0; i < AF; i++) {
        #pragma unroll
        for (int j = 0; j < BF; j++) {
            #pragma unroll
            for (int r = 0; r < 4; r++) {
                int row = m0 + wr + i * 16 + qd * 4 + r;
                int col = n0 + wc + j * 16 + mi;
                float v = acc[i][j][r];
                if (EPI == 3) {
                    v += bias[row];                 // per-row bias (V^T output)
                    outH[(size_t)row * N + col] = (_Float16)v;
                } else if (EPI == 5) {
                    if (doBias) v += bias[col];
                    oH[(size_t)row * N + col] = (_Float16)v;
                } else {
                    if (doBias) v += bias[col];
                    if (RELU) v = fmaxf(v, 0.f);
                    size_t off = (size_t)row * N + col;
                    if (oF) oF[off] = v;
                    if (outH) outH[off] = (_Float16)v;
                }
            }
        }
    }
}

// ---- GEMM(N=512) + residual + LayerNorm, FULL-ROW 16-row blocks -----------
// C[4096,512] = A[4096,KK] x Bt[512,KK]^T + bias; out = LN(res + C).
// Block: 16 rows x ALL 512 cols, 4 waves (wave w owns cols [w*128,(w+1)*128)).
// 256 blocks -> every CU active. LDS ~68 KB. acc = 32 VGPR. f32 end-to-end.
// LN intra-block: shfl over mi + 512B LDS cross-wave reduce. No x-block sync.
template<int KK, typename RT>
__global__ __launch_bounds__(256)
void oproj_ln(const _Float16* __restrict__ A, const _Float16* __restrict__ Bt,
              const float* __restrict__ bias, const RT* __restrict__ res,
              const float* __restrict__ lng, const float* __restrict__ lnb,
              float* __restrict__ outF, _Float16* __restrict__ outH) {
    __shared__ _Float16 smem[66 * 512];      // A 16x64 (2 chunks) | B 512x64
    __shared__ float sred[4][16], qred[4][16];
    const int tid = threadIdx.x;
    const int wid = tid >> 6, lid = tid & 63;
    const int mi = lid & 15, qd = lid >> 4;
    const int m0 = blockIdx.x * 16;
    const int wc = wid * 128;
    const _Float16* Ap = A + (size_t)m0 * KK;
    const int lrow = lid >> 3;
    const int gblk = (lid & 7) ^ ((lid >> 3) & 7);
    auto stage = [&](int kt) {
        if (wid < 2) {                       // A: 2 chunks (16 rows)
            int row = wid * 8 + lrow;
            __builtin_amdgcn_global_load_lds(
                (const AS1 unsigned int*)(Ap + (size_t)row * KK + kt * 64 + gblk * 8),
                (AS3 unsigned int*)&smem[wid * 512], 16, 0, 0);
        }
        #pragma unroll
        for (int l = 0; l < 16; l++) {       // B: 64 chunks (512 rows)
            int c = l * 4 + wid;
            int row = c * 8 + lrow;
            __builtin_amdgcn_global_load_lds(
                (const AS1 unsigned int*)(Bt + (size_t)row * KK + kt * 64 + gblk * 8),
                (AS3 unsigned int*)&smem[(2 + c) * 512], 16, 0, 0);
        }
    };
    f32x4 acc[8] = {};
    constexpr int NIT = KK / 64;
    stage(0);
    __builtin_amdgcn_s_waitcnt(0x0F70);
    __syncthreads();
    for (int t = 0; t < NIT; t++) {
        #pragma unroll
        for (int h = 0; h < 2; h++) {
            const int sA = ((4 * h + qd) ^ (mi & 7)) * 8;
            half8 af = *(const half8*)&smem[mi * 64 + sA];
            half8 bfr[8];
            #pragma unroll
            for (int j = 0; j < 8; j++)
                bfr[j] = *(const half8*)&smem[1024 + (wc + j * 16 + mi) * 64 + sA];
            #pragma unroll
            for (int j = 0; j < 8; j++)
                acc[j] = __builtin_amdgcn_mfma_f32_16x16x32_f16(af, bfr[j], acc[j], 0, 0, 0);
        }
        if (t + 1 < NIT) {
            __syncthreads();
            stage(t + 1);
            __builtin_amdgcn_s_waitcnt(0x0F70);
            __syncthreads();
        }
    }
    // ---- bias + residual; per-row partial stats ----
    float ps[4] = {0.f, 0.f, 0.f, 0.f}, pq[4] = {0.f, 0.f, 0.f, 0.f};
    #pragma unroll
    for (int j = 0; j < 8; j++) {
        int col = wc + j * 16 + mi;
        float bj = bias[col];
        #pragma unroll
        for (int r = 0; r < 4; r++) {
            int row = m0 + qd * 4 + r;
            float x = acc[j][r] + bj + (float)res[(size_t)row * 512 + col];
            acc[j][r] = x;
            ps[r] += x; pq[r] += x * x;
        }
    }
    #pragma unroll
    for (int r = 0; r < 4; r++) {
        float s = ps[r], q = pq[r];
        s += __shfl_xor(s, 1, 64); q += __shfl_xor(q, 1, 64);
        s += __shfl_xor(s, 2, 64); q += __shfl_xor(q, 2, 64);
        s += __shfl_xor(s, 4, 64); q += __shfl_xor(q, 4, 64);
        s += __shfl_xor(s, 8, 64); q += __shfl_xor(q, 8, 64);
        if (mi == 0) { sred[wid][qd * 4 + r] = s; qred[wid][qd * 4 + r] = q; }
    }
    __syncthreads();
    #pragma unroll
    for (int r = 0; r < 4; r++) {
        int lr = qd * 4 + r;
        float ts = sred[0][lr] + sred[1][lr] + sred[2][lr] + sred[3][lr];
        float tq = qred[0][lr] + qred[1][lr] + qred[2][lr] + qred[3][lr];
        float mu = ts * (1.f / 512.f);
        float var = tq * (1.f / 512.f) - mu * mu;
        float rs = rsqrtf(var + 1e-6f);
        int row = m0 + lr;
        #pragma unroll
        for (int j = 0; j < 8; j++) {
            int col = wc + j * 16 + mi;
            float o = (acc[j][r] - mu) * rs * lng[col] + lnb[col];
            if (outF) outF[(size_t)row * 512 + col] = o;
            if (outH) outH[(size_t)row * 512 + col] = (_Float16)o;
        }
    }
}

// -------- monolithic MFMA flash attention, 8 waves = 2 key-streams x 4 ------
template<bool CAUSAL>
__global__ __launch_bounds__(512)
void attn_mono(const _Float16* __restrict__ Qh, const _Float16* __restrict__ Kh,
               const _Float16* __restrict__ VT, int ldv,
               _Float16* __restrict__ O) {
    const int x = blockIdx.x, bh = blockIdx.y;
    int qt;
    if (CAUSAL) {
        int half = x >> 1;
        int pick = (x & 1) ^ ((bh >> 3) & 1);
        qt = pick ? half : 31 - half;
    } else {
        qt = x;
    }
    const int nt = CAUSAL ? (qt + 1) : 32;
    const int np = (nt + 1) >> 1;          // lockstep iterations (both streams)
    __shared__ _Float16 Qs[64 * 64];
    __shared__ _Float16 Ps[2][64 * 64];    // per-stream P buffer
    __shared__ _Float16 Ks[2][64 * 64];    // per-stream K tile (single-buffered)
    __shared__ _Float16 Vs[2][64 * 64];
    __shared__ float Lsh[64];
    const int tid = threadIdx.x, w = tid >> 6, lane = tid & 63;
    const int w4 = w & 3, st = w >> 2;
    const int mi = lane & 15, qd = lane >> 4;
    const int qbase = qt * 64;
    const int b = bh >> 3, h = bh & 7;
    const _Float16* Qp = Qh + ((size_t)bh * SEQ + qbase) * 64;
    const _Float16* Kp = Kh + (size_t)bh * SEQ * 64;
    const _Float16* Vp = VT + (size_t)(h * 64) * ldv + (size_t)b * SEQ;
    const int lrow = lane >> 3;
    const int gblk = (lane & 7) ^ ((lane >> 3) & 7);
    const int f0 = (qd ^ (mi & 7)) * 8;
    const int f1 = ((qd + 4) ^ (mi & 7)) * 8;

    { // Q staging: 512 threads, one row-segment each
        int r0 = tid >> 3, blk = tid & 7;
        int sw = (blk ^ (r0 & 7)) * 8;
        half8 q0 = *(const half8*)(Qp + r0 * 64 + blk * 8);
        *(half8*)&Qs[r0 * 64 + sw] = q0;
    }
    __syncthreads();
    half8 qb0 = *(half8*)&Qs[(w4 * 16 + mi) * 64 + f0];
    half8 qb1 = *(half8*)&Qs[(w4 * 16 + mi) * 64 + f1];
    f32x4 oacc[4] = {};
    float lacc = 0.f;
    _Float16* Pst = Ps[st];

    for (int i = 0; i < np; i++) {
        const int t = 2 * i + st;
        const bool act = t < nt;           // uniform within a stream
        __syncthreads();                   // own-region LDS free for restage
        if (act) {
            #pragma unroll
            for (int l = 0; l < 2; l++) {
                int cc = l * 4 + w4;
                int row = cc * 8 + lrow;
                __builtin_amdgcn_global_load_lds(
                    (const AS1 unsigned int*)(Kp + ((size_t)(t * 64 + row)) * 64 + gblk * 8),
                    (AS3 unsigned int*)&Ks[st][cc * 512], 16, 0, 0);
                __builtin_amdgcn_global_load_lds(
                    (const AS1 unsigned int*)(Vp + (size_t)row * ldv + t * 64 + gblk * 8),
                    (AS3 unsigned int*)&Vs[st][cc * 512], 16, 0, 0);
            }
        }
        __builtin_amdgcn_s_waitcnt(0x0F70);
        __syncthreads();                   // staged tile visible to stream
        if (!act) continue;                // barrier counts stay uniform
        const _Float16* ksb = Ks[st];
        const _Float16* vsb = Vs[st];
        f32x4 s[4];
        #pragma unroll
        for (int j = 0; j < 4; j++) {
            half8 ka0 = *(const half8*)&ksb[(j * 16 + mi) * 64 + f0];
            half8 ka1 = *(const half8*)&ksb[(j * 16 + mi) * 64 + f1];
            f32x4 a = {};
            a = __builtin_amdgcn_mfma_f32_16x16x32_f16(ka0, qb0, a, 0, 0, 0);
            a = __builtin_amdgcn_mfma_f32_16x16x32_f16(ka1, qb1, a, 0, 0, 0);
            s[j] = a;
        }
        if (CAUSAL && t == qt) {
            int qg = qbase + w4 * 16 + mi;
            #pragma unroll
            for (int j = 0; j < 4; j++)
                #pragma unroll
                for (int r = 0; r < 4; r++) {
                    int key = t * 64 + j * 16 + qd * 4 + r;
                    if (key > qg) s[j][r] = -1e30f;
                }
        }
        #pragma unroll
        for (int j = 0; j < 4; j++)
            #pragma unroll
            for (int r = 0; r < 4; r++) {
                float pv = __builtin_amdgcn_exp2f(s[j][r]);
                s[j][r] = pv;
                lacc += pv;
            }
        #pragma unroll
        for (int j = 0; j < 4; j++) {
            fp16x2 lo = __builtin_amdgcn_cvt_pkrtz(s[j][0], s[j][1]);
            fp16x2 hi = __builtin_amdgcn_cvt_pkrtz(s[j][2], s[j][3]);
            half2_t lo2 = __builtin_bit_cast(half2_t, lo);
            half2_t hi2 = __builtin_bit_cast(half2_t, hi);
            half4 pq;
            pq[0] = lo2[0]; pq[1] = lo2[1]; pq[2] = hi2[0]; pq[3] = hi2[1];
            int blkp = (2 * j + (qd >> 1)) ^ (mi & 7);
            *(half4*)&Pst[(w4 * 16 + mi) * 64 + blkp * 8 + (qd & 1) * 4] = pq;
        }
        half8 pa0 = *(half8*)&Pst[(w4 * 16 + mi) * 64 + f0];
        half8 pa1 = *(half8*)&Pst[(w4 * 16 + mi) * 64 + f1];
        #pragma unroll
        for (int j = 0; j < 4; j++) {
            half8 vb0 = *(const half8*)&vsb[(j * 16 + mi) * 64 + f0];
            half8 vb1 = *(const half8*)&vsb[(j * 16 + mi) * 64 + f1];
            oacc[j] = __builtin_amdgcn_mfma_f32_16x16x32_f16(pa0, vb0, oacc[j], 0, 0, 0);
            oacc[j] = __builtin_amdgcn_mfma_f32_16x16x32_f16(pa1, vb1, oacc[j], 0, 0, 0);
        }
    }
    __syncthreads();                       // all compute done; K/V reusable
    if (st == 1) {                         // dump stream-1 partials
        float* obuf = (float*)Ks;          // 16 KB = 4 waves x 64 x 16 f32
        float* lbuf = (float*)Vs;
        int base = (w4 * 64 + lane) * 16;
        #pragma unroll
        for (int j = 0; j < 4; j++)
            #pragma unroll
            for (int r = 0; r < 4; r++)
                obuf[base + j * 4 + r] = oacc[j][r];
        lbuf[w4 * 64 + lane] = lacc;
    }
    __syncthreads();
    if (st == 0) {                         // merge + L reduce
        const float* obuf = (const float*)Ks;
        const float* lbuf = (const float*)Vs;
        int base = (w4 * 64 + lane) * 16;
        #pragma unroll
        for (int j = 0; j < 4; j++)
            #pragma unroll
            for (int r = 0; r < 4; r++)
                oacc[j][r] += obuf[base + j * 4 + r];
        lacc += lbuf[w4 * 64 + lane];
        lacc += __shfl_xor(lacc, 16, 64);
        lacc += __shfl_xor(lacc, 32, 64);
        if (qd == 0) Lsh[w4 * 16 + mi] = lacc;
    }
    __syncthreads();
    if (st == 0) {
        #pragma unroll
        for (int r = 0; r < 4; r++) {
            float rl = 1.f / Lsh[w4 * 16 + qd * 4 + r];
            int qrow = qbase + w4 * 16 + qd * 4 + r;
            size_t obase = ((size_t)(b * SEQ + qrow)) * 512 + h * 64;
            #pragma unroll
            for (int j = 0; j < 4; j++)
                O[obase + j * 16 + mi] = (_Float16)(oacc[j][r] * rl);
        }
    }
}

extern "C" void kernel_launch(void* const* d_in, const int* in_sizes, int n_in,
                              void* d_out, int out_size, void* d_ws, size_t ws_size,
                              hipStream_t stream) {
    (void)in_sizes; (void)n_in; (void)out_size; (void)ws_size;
    const float* inp  = (const float*)d_in[0];
    const float* enc  = (const float*)d_in[1];
    const float* q1_w = (const float*)d_in[4];
    const float* q1_b = (const float*)d_in[5];
    const float* k1_w = (const float*)d_in[6];
    const float* k1_b = (const float*)d_in[7];
    const float* v1_w = (const float*)d_in[8];
    const float* v1_b = (const float*)d_in[9];
    const float* o1_w = (const float*)d_in[10];
    const float* o1_b = (const float*)d_in[11];
    const float* q2_w = (const float*)d_in[12];
    const float* q2_b = (const float*)d_in[13];
    const float* k2_w = (const float*)d_in[14];
    const float* k2_b = (const float*)d_in[15];
    const float* v2_w = (const float*)d_in[16];
    const float* v2_b = (const float*)d_in[17];
    const float* o2_w = (const float*)d_in[18];
    const float* o2_b = (const float*)d_in[19];
    const float* f1_w = (const float*)d_in[20];
    const float* f1_b = (const float*)d_in[21];
    const float* f2_w = (const float*)d_in[22];
    const float* f2_b = (const float*)d_in[23];
    const float* ln1_g = (const float*)d_in[24];
    const float* ln1_b = (const float*)d_in[25];
    const float* ln2_g = (const float*)d_in[26];
    const float* ln2_b = (const float*)d_in[27];
    const float* ln3_g = (const float*)d_in[28];
    const float* ln3_b = (const float*)d_in[29];

    char* p = (char*)d_ws;
    auto alloc = [&](size_t bytes) { char* r = p; p += (bytes + 255) & ~(size_t)255; return (void*)r; };
    _Float16* xh    = (_Float16*)alloc((size_t)M * DM * 2);
    _Float16* eh    = (_Float16*)alloc((size_t)M * DM * 2);
    _Float16* qk1t  = (_Float16*)alloc((size_t)1024 * DM * 2);
    _Float16* v1t   = (_Float16*)alloc((size_t)DM * DM * 2);
    _Float16* o1t   = (_Float16*)alloc((size_t)DM * DM * 2);
    _Float16* qk2t  = (_Float16*)alloc((size_t)1024 * DM * 2);
    _Float16* v2t   = (_Float16*)alloc((size_t)DM * DM * 2);
    _Float16* o2t   = (_Float16*)alloc((size_t)DM * DM * 2);
    _Float16* f1t   = (_Float16*)alloc((size_t)FFD * DM * 2);
    _Float16* f2t   = (_Float16*)alloc((size_t)DM * FFD * 2);
    float* qk1b     = (float*)alloc(1024 * 4);
    float* qk2b     = (float*)alloc(1024 * 4);
    _Float16* Qh1   = (_Float16*)alloc((size_t)M * DM * 2);
    _Float16* Kh1   = (_Float16*)alloc((size_t)M * DM * 2);
    _Float16* Qh2   = (_Float16*)alloc((size_t)M * DM * 2);
    _Float16* Kh2   = (_Float16*)alloc((size_t)M * DM * 2);
    _Float16* V1T   = (_Float16*)alloc((size_t)DM * M * 2);
    _Float16* V2T   = (_Float16*)alloc((size_t)DM * M * 2);
    _Float16* Ah    = (_Float16*)alloc((size_t)M * DM * 2);
    _Float16* out1h = (_Float16*)alloc((size_t)M * DM * 2);
    _Float16* out2h = (_Float16*)alloc((size_t)M * DM * 2);
    _Float16* hh    = (_Float16*)alloc((size_t)M * FFD * 2);

    dim3 t256(256), t512(512);
    // 1) all preprocessing in one launch
    preproc<<<dim3(1026 + 2048), t256, 0, stream>>>(
        q1_w, k1_w, v1_w, o1_w, q2_w, k2_w, v2_w, o2_w, f1_w, f2_w,
        qk1t, v1t, o1t, qk2t, v2t, o2t, f1t, f2t,
        q1_b, k1_b, q2_b, k2_b, qk1b, qk2b, inp, enc, xh, eh);

    // 2) QK projections (both) + V1^T in ONE launch: 1280 blocks (5/CU)
    qkv_gemm<<<dim3(1280), t256, 0, stream>>>(
        xh, eh, qk1t, qk2t, qk1b, qk2b, Qh1, Kh1, Qh2, Kh2, v1t, v1_b, V1T);

    // 3) self attention (causal, 8-wave dual-stream, CU-pair balanced)
    attn_mono<true><<<dim3(32, 16), t512, 0, stream>>>(Qh1, Kh1, V1T, M, Ah);
    // 4) O1-projection + residual(inp f32) + LN1 -> out1h  (fused, 256 blocks)
    oproj_ln<512, float><<<dim3(256), t256, 0, stream>>>(
        Ah, o1t, o1_b, inp, ln1_g, ln1_b, nullptr, out1h);

    // 5) V2^T = v2_w^T . out1^T
    gemm_tn<64, 64, 32, 32, false, 3, 1><<<dim3(64, 8), t256, 0, stream>>>(
        v2t, out1h, v2_b, nullptr, V2T, 512, M, 512);
    // 6) cross attention
    attn_mono<false><<<dim3(32, 16), t512, 0, stream>>>(Qh2, Kh2, V2T, M, Ah);
    // 7) O2-projection + residual(out1h f16) + LN2 -> out2h  (fused, 256 blocks)
    oproj_ln<512, _Float16><<<dim3(256), t256, 0, stream>>>(
        Ah, o2t, o2_b, out1h, ln2_g, ln2_b, nullptr, out2h);

    // 8) FFN1
    gemm_tn<128, 64, 64, 32, true, 0, 1><<<dim3(32, 32), t256, 0, stream>>>(
        out2h, f1t, f1_b, nullptr, hh, M, 2048, 512);
    // 9) FFN2 + residual(out2h f16) + LN3 -> d_out (fused, 256 blocks, K=2048)
    oproj_ln<2048, _Float16><<<dim3(256), t256, 0, stream>>>(
        hh, f2t, f2_b, out2h, ln3_g, ln3_b, (float*)d_out, nullptr);
}

// Round 16
// 287.065 us; speedup vs baseline: 1.1203x; 1.1203x over previous
//
#include <hip/hip_runtime.h>

typedef __attribute__((ext_vector_type(8))) _Float16 half8;
typedef __attribute__((ext_vector_type(4))) _Float16 half4;
typedef __attribute__((ext_vector_type(2))) _Float16 half2_t;
typedef __attribute__((ext_vector_type(2))) __fp16 fp16x2;
typedef __attribute__((ext_vector_type(4))) float f32x4;

#define AS1 __attribute__((address_space(1)))
#define AS3 __attribute__((address_space(3)))

constexpr int SEQ = 2048, DM = 512, FFD = 2048, NH = 8, DH = 64;
constexpr int M = 2 * SEQ; // 4096 rows
constexpr float QSCALE = 0.125f * 1.4426950408889634f; // 1/sqrt(64) * log2(e)

// ======== fused preprocessing: 10 weight transposes + biases + 2 casts ======
__global__ __launch_bounds__(256)
void preproc(const float* __restrict__ q1_w, const float* __restrict__ k1_w,
             const float* __restrict__ v1_w, const float* __restrict__ o1_w,
             const float* __restrict__ q2_w, const float* __restrict__ k2_w,
             const float* __restrict__ v2_w, const float* __restrict__ o2_w,
             const float* __restrict__ f1_w, const float* __restrict__ f2_w,
             _Float16* __restrict__ qk1t, _Float16* __restrict__ v1t,
             _Float16* __restrict__ o1t, _Float16* __restrict__ qk2t,
             _Float16* __restrict__ v2t, _Float16* __restrict__ o2t,
             _Float16* __restrict__ f1t, _Float16* __restrict__ f2t,
             const float* __restrict__ q1_b, const float* __restrict__ k1_b,
             const float* __restrict__ q2_b, const float* __restrict__ k2_b,
             float* __restrict__ qk1b, float* __restrict__ qk2b,
             const float* __restrict__ inp, const float* __restrict__ enc,
             _Float16* __restrict__ xh, _Float16* __restrict__ eh) {
    __shared__ _Float16 tile[64 * 65];
    const int j = blockIdx.x, tid = threadIdx.x;
    if (j < 1024) {
        const float* src; _Float16* dst; int K, N, n0, k0;
        if (j < 512) {
            int w8 = j >> 6, t = j & 63;
            K = 512; N = 512; n0 = (t & 7) * 64; k0 = (t >> 3) * 64;
            switch (w8) {
                case 0: src = q1_w; dst = qk1t; break;
                case 1: src = k1_w; dst = qk1t + 512 * 512; break;
                case 2: src = v1_w; dst = v1t; break;
                case 3: src = o1_w; dst = o1t; break;
                case 4: src = q2_w; dst = qk2t; break;
                case 5: src = k2_w; dst = qk2t + 512 * 512; break;
                case 6: src = v2_w; dst = v2t; break;
                default: src = o2_w; dst = o2t; break;
            }
        } else if (j < 768) {
            int t = j - 512; K = 512; N = 2048;
            n0 = (t % 32) * 64; k0 = (t / 32) * 64; src = f1_w; dst = f1t;
        } else {
            int t = j - 768; K = 2048; N = 512;
            n0 = (t % 8) * 64; k0 = (t / 8) * 64; src = f2_w; dst = f2t;
        }
        int c = tid & 63, r4 = tid >> 6;
        for (int i = 0; i < 16; i++) {
            int r = r4 * 16 + i;
            tile[r * 65 + c] = (_Float16)src[(size_t)(k0 + r) * N + n0 + c];
        }
        __syncthreads();
        for (int i = 0; i < 16; i++) {
            int r = r4 * 16 + i;
            dst[(size_t)(n0 + r) * K + k0 + c] = tile[c * 65 + r];
        }
    } else if (j == 1024) {
        for (int i = tid; i < 512; i += 256) { qk1b[i] = q1_b[i]; qk1b[512 + i] = k1_b[i]; }
    } else if (j == 1025) {
        for (int i = tid; i < 512; i += 256) { qk2b[i] = q2_b[i]; qk2b[512 + i] = k2_b[i]; }
    } else {
        int k = j - 1026;                        // 0..2047
        const float* s = (k < 1024) ? inp : enc;
        _Float16* d = (k < 1024) ? xh : eh;
        size_t base = (size_t)(k & 1023) * 2048 + tid * 8;
        f32x4 a = *(const f32x4*)(s + base);
        f32x4 b2 = *(const f32x4*)(s + base + 4);
        half8 h;
        h[0] = (_Float16)a[0]; h[1] = (_Float16)a[1];
        h[2] = (_Float16)a[2]; h[3] = (_Float16)a[3];
        h[4] = (_Float16)b2[0]; h[5] = (_Float16)b2[1];
        h[6] = (_Float16)b2[2]; h[7] = (_Float16)b2[3];
        *(half8*)(d + base) = h;
    }
}

// ---- merged QK-projection (jobs 0..1023) + V1^T GEMM (jobs 1024..1279) ----
__global__ __launch_bounds__(256)
void qkv_gemm(const _Float16* __restrict__ xh, const _Float16* __restrict__ eh,
              const _Float16* __restrict__ qk1t, const _Float16* __restrict__ qk2t,
              const float* __restrict__ qk1b, const float* __restrict__ qk2b,
              _Float16* __restrict__ Qh1, _Float16* __restrict__ Kh1,
              _Float16* __restrict__ Qh2, _Float16* __restrict__ Kh2,
              const _Float16* __restrict__ v1t, const float* __restrict__ v1b,
              _Float16* __restrict__ V1T) {
    __shared__ _Float16 smem[192 * 64];
    const int tid = threadIdx.x;
    const int wid = tid >> 6, lid = tid & 63;
    const int wr = (wid & 1) * 64;
    const int wc = (wid >> 1) * 32;
    const int mi = lid & 15, qd = lid >> 4;
    const int jb = blockIdx.x;
    const _Float16 *Ap, *Bp;
    const float* bias;
    int m0, n0, epi, job = 0;
    if (jb < 1024) {
        epi = 4; job = jb >> 9;
        int L = jb & 511;
        int by = L % 32, bx = L / 32;
        m0 = by * 128; n0 = bx * 64;
        Ap = (job ? eh : xh) + (size_t)m0 * 512;
        Bp = (job ? qk2t : qk1t) + (size_t)n0 * 512;
        bias = job ? qk2b : qk1b;
    } else {
        epi = 3;
        int t = jb - 1024;
        int by = t & 3, bx = t >> 2;
        m0 = by * 128; n0 = bx * 64;
        Ap = v1t + (size_t)m0 * 512;
        Bp = xh + (size_t)n0 * 512;
        bias = v1b;
    }
    const int lrow = lid >> 3;
    const int gblk = (lid & 7) ^ ((lid >> 3) & 7);
    auto stage = [&](int kt) {
        #pragma unroll
        for (int l = 0; l < 4; l++) {
            int c = l * 4 + wid;
            int row = c * 8 + lrow;
            __builtin_amdgcn_global_load_lds(
                (const AS1 unsigned int*)(Ap + (size_t)row * 512 + kt * 64 + gblk * 8),
                (AS3 unsigned int*)&smem[c * 512], 16, 0, 0);
        }
        #pragma unroll
        for (int l = 0; l < 2; l++) {
            int c = l * 4 + wid;
            int row = c * 8 + lrow;
            __builtin_amdgcn_global_load_lds(
                (const AS1 unsigned int*)(Bp + (size_t)row * 512 + kt * 64 + gblk * 8),
                (AS3 unsigned int*)&smem[128 * 64 + c * 512], 16, 0, 0);
        }
    };
    f32x4 acc[4][2] = {};
    stage(0);
    __builtin_amdgcn_s_waitcnt(0x0F70);
    __syncthreads();
    for (int t = 0; t < 8; t++) {
        #pragma unroll
        for (int h = 0; h < 2; h++) {
            const int sA = ((4 * h + qd) ^ (mi & 7)) * 8;
            half8 af[4], bfr[2];
            #pragma unroll
            for (int i = 0; i < 4; i++)
                af[i] = *(const half8*)&smem[(wr + i * 16 + mi) * 64 + sA];
            #pragma unroll
            for (int j = 0; j < 2; j++)
                bfr[j] = *(const half8*)&smem[(128 + wc + j * 16 + mi) * 64 + sA];
            #pragma unroll
            for (int i = 0; i < 4; i++)
                #pragma unroll
                for (int j = 0; j < 2; j++)
                    acc[i][j] = __builtin_amdgcn_mfma_f32_16x16x32_f16(af[i], bfr[j], acc[i][j], 0, 0, 0);
        }
        if (t + 1 < 8) {
            __syncthreads();
            stage(t + 1);
            __builtin_amdgcn_s_waitcnt(0x0F70);
            __syncthreads();
        }
    }
    #pragma unroll
    for (int i = 0; i < 4; i++) {
        #pragma unroll
        for (int j = 0; j < 2; j++) {
            #pragma unroll
            for (int r = 0; r < 4; r++) {
                int row = m0 + wr + i * 16 + qd * 4 + r;
                int col = n0 + wc + j * 16 + mi;
                float v = acc[i][j][r];
                if (epi == 4) {
                    v += bias[col];
                    int hh2 = (col >> 6) & 7, d = col & 63;
                    int bb = row >> 11, nn = row & 2047;
                    size_t idx = (((size_t)bb * 8 + hh2) * SEQ + nn) * 64 + d;
                    if (col < 512) (job ? Qh2 : Qh1)[idx] = (_Float16)(v * QSCALE);
                    else           (job ? Kh2 : Kh1)[idx] = (_Float16)v;
                } else {
                    v += bias[row];                 // per-row bias (V^T output)
                    V1T[(size_t)row * 4096 + col] = (_Float16)v;
                }
            }
        }
    }
}

// -------- GEMM: C = A[M,K] * Bt[N,K]^T + bias, f16 in / f32 acc --------
// EPI 0: plain. EPI 3: transposed-V out (per-ROW bias). EPI 5: split-K slices.
template<int BM, int BN, int WM, int WN, bool RELU, int EPI, int SPLIT>
__global__ __launch_bounds__(256)
void gemm_tn(const _Float16* __restrict__ A, const _Float16* __restrict__ Bt,
             const float* __restrict__ bias,
             float* __restrict__ outF, _Float16* __restrict__ outH,
             int Mtot, int N, int K) {
    constexpr int ROWS = BM + BN;
    __shared__ _Float16 smem[ROWS * 64];
    constexpr int AF = WM / 16, BF = WN / 16;
    constexpr int WROW = BM / WM;
    const int tid = threadIdx.x;
    const int wid = tid >> 6, lid = tid & 63;
    const int wr = (wid % WROW) * WM;
    const int wc = (wid / WROW) * WN;
    const int mi = lid & 15, qd = lid >> 4;
    const int gx = gridDim.x, gy = gridDim.y;
    const int L = blockIdx.y * gx + blockIdx.x;
    const int by = L % gy, bx = L / gy;
    const int m0 = by * BM, n0 = bx * BN;
    const int Kc = K / SPLIT;
    const int kbase = (SPLIT > 1) ? blockIdx.z * Kc : 0;
    const _Float16* Ap = A + (size_t)m0 * K + kbase;
    const _Float16* Bp = Bt + (size_t)n0 * K + kbase;
    const int lrow = lid >> 3;
    const int gblk = (lid & 7) ^ ((lid >> 3) & 7);
    auto stage = [&](int kt) {
        #pragma unroll
        for (int l = 0; l < BM / 32; l++) {
            int c = l * 4 + wid;
            int row = c * 8 + lrow;
            __builtin_amdgcn_global_load_lds(
                (const AS1 unsigned int*)(Ap + (size_t)row * K + kt * 64 + gblk * 8),
                (AS3 unsigned int*)&smem[c * 512], 16, 0, 0);
        }
        #pragma unroll
        for (int l = 0; l < BN / 32; l++) {
            int c = l * 4 + wid;
            int row = c * 8 + lrow;
            __builtin_amdgcn_global_load_lds(
                (const AS1 unsigned int*)(Bp + (size_t)row * K + kt * 64 + gblk * 8),
                (AS3 unsigned int*)&smem[BM * 64 + c * 512], 16, 0, 0);
        }
    };
    f32x4 acc[AF][BF] = {};
    const int NIT = Kc / 64;
    stage(0);
    __builtin_amdgcn_s_waitcnt(0x0F70);
    __syncthreads();
    for (int t = 0; t < NIT; t++) {
        #pragma unroll
        for (int h = 0; h < 2; h++) {
            const int sA = ((4 * h + qd) ^ (mi & 7)) * 8;
            half8 af[AF], bfr[BF];
            #pragma unroll
            for (int i = 0; i < AF; i++)
                af[i] = *(const half8*)&smem[(wr + i * 16 + mi) * 64 + sA];
            #pragma unroll
            for (int j = 0; j < BF; j++)
                bfr[j] = *(const half8*)&smem[(BM + wc + j * 16 + mi) * 64 + sA];
            #pragma unroll
            for (int i = 0; i < AF; i++)
                #pragma unroll
                for (int j = 0; j < BF; j++)
                    acc[i][j] = __builtin_amdgcn_mfma_f32_16x16x32_f16(af[i], bfr[j], acc[i][j], 0, 0, 0);
        }
        if (t + 1 < NIT) {
            __syncthreads();
            stage(t + 1);
            __builtin_amdgcn_s_waitcnt(0x0F70);
            __syncthreads();
        }
    }
    float* oF = outF;
    if (SPLIT > 1 && outF) oF = outF + (size_t)blockIdx.z * Mtot * N;
    _Float16* oH = outH;
    if (EPI == 5) oH = outH + (size_t)blockIdx.z * Mtot * N;
    const bool doBias = bias && (SPLIT == 1 || blockIdx.z == 0);
    #pragma unroll
    for (int i = 0; i < AF; i++) {
        #pragma unroll
        for (int j = 0; j < BF; j++) {
            #pragma unroll
            for (int r = 0; r < 4; r++) {
                int row = m0 + wr + i * 16 + qd * 4 + r;
                int col = n0 + wc + j * 16 + mi;
                float v = acc[i][j][r];
                if (EPI == 3) {
                    v += bias[row];                 // per-row bias (V^T output)
                    outH[(size_t)row * N + col] = (_Float16)v;
                } else if (EPI == 5) {
                    if (doBias) v += bias[col];
                    oH[(size_t)row * N + col] = (_Float16)v;
                } else {
                    if (doBias) v += bias[col];
                    if (RELU) v = fmaxf(v, 0.f);
                    size_t off = (size_t)row * N + col;
                    if (oF) oF[off] = v;
                    if (outH) outH[off] = (_Float16)v;
                }
            }
        }
    }
}

// ---- O-projection + residual + LayerNorm, FULL-ROW 16-row blocks ----------
// C[4096,512] = A[4096,512] x Bt[512,512]^T + bias; out = LN(res + C).
// Block: 16 rows x ALL 512 cols, 4 waves (wave w owns cols [w*128,(w+1)*128)).
// 256 blocks -> every CU active. LDS ~68 KB. acc = 32 VGPR. No x-block sync.
template<typename RT>
__global__ __launch_bounds__(256)
void oproj_ln(const _Float16* __restrict__ A, const _Float16* __restrict__ Bt,
              const float* __restrict__ bias, const RT* __restrict__ res,
              const float* __restrict__ lng, const float* __restrict__ lnb,
              _Float16* __restrict__ outH) {
    __shared__ _Float16 smem[66 * 512];      // A 16x64 (2 chunks) | B 512x64
    __shared__ float sred[4][16], qred[4][16];
    const int tid = threadIdx.x;
    const int wid = tid >> 6, lid = tid & 63;
    const int mi = lid & 15, qd = lid >> 4;
    const int m0 = blockIdx.x * 16;
    const int wc = wid * 128;
    const _Float16* Ap = A + (size_t)m0 * 512;
    const int lrow = lid >> 3;
    const int gblk = (lid & 7) ^ ((lid >> 3) & 7);
    auto stage = [&](int kt) {
        if (wid < 2) {                       // A: 2 chunks (16 rows)
            int row = wid * 8 + lrow;
            __builtin_amdgcn_global_load_lds(
                (const AS1 unsigned int*)(Ap + (size_t)row * 512 + kt * 64 + gblk * 8),
                (AS3 unsigned int*)&smem[wid * 512], 16, 0, 0);
        }
        #pragma unroll
        for (int l = 0; l < 16; l++) {       // B: 64 chunks (512 rows)
            int c = l * 4 + wid;
            int row = c * 8 + lrow;
            __builtin_amdgcn_global_load_lds(
                (const AS1 unsigned int*)(Bt + (size_t)row * 512 + kt * 64 + gblk * 8),
                (AS3 unsigned int*)&smem[(2 + c) * 512], 16, 0, 0);
        }
    };
    f32x4 acc[8] = {};
    stage(0);
    __builtin_amdgcn_s_waitcnt(0x0F70);
    __syncthreads();
    for (int t = 0; t < 8; t++) {
        #pragma unroll
        for (int h = 0; h < 2; h++) {
            const int sA = ((4 * h + qd) ^ (mi & 7)) * 8;
            half8 af = *(const half8*)&smem[mi * 64 + sA];
            half8 bfr[8];
            #pragma unroll
            for (int j = 0; j < 8; j++)
                bfr[j] = *(const half8*)&smem[1024 + (wc + j * 16 + mi) * 64 + sA];
            #pragma unroll
            for (int j = 0; j < 8; j++)
                acc[j] = __builtin_amdgcn_mfma_f32_16x16x32_f16(af, bfr[j], acc[j], 0, 0, 0);
        }
        if (t + 1 < 8) {
            __syncthreads();
            stage(t + 1);
            __builtin_amdgcn_s_waitcnt(0x0F70);
            __syncthreads();
        }
    }
    // ---- bias + residual; per-row partial stats ----
    float ps[4] = {0.f, 0.f, 0.f, 0.f}, pq[4] = {0.f, 0.f, 0.f, 0.f};
    #pragma unroll
    for (int j = 0; j < 8; j++) {
        int col = wc + j * 16 + mi;
        float bj = bias[col];
        #pragma unroll
        for (int r = 0; r < 4; r++) {
            int row = m0 + qd * 4 + r;
            float x = acc[j][r] + bj + (float)res[(size_t)row * 512 + col];
            acc[j][r] = x;
            ps[r] += x; pq[r] += x * x;
        }
    }
    #pragma unroll
    for (int r = 0; r < 4; r++) {
        float s = ps[r], q = pq[r];
        s += __shfl_xor(s, 1, 64); q += __shfl_xor(q, 1, 64);
        s += __shfl_xor(s, 2, 64); q += __shfl_xor(q, 2, 64);
        s += __shfl_xor(s, 4, 64); q += __shfl_xor(q, 4, 64);
        s += __shfl_xor(s, 8, 64); q += __shfl_xor(q, 8, 64);
        if (mi == 0) { sred[wid][qd * 4 + r] = s; qred[wid][qd * 4 + r] = q; }
    }
    __syncthreads();
    #pragma unroll
    for (int r = 0; r < 4; r++) {
        int lr = qd * 4 + r;
        float ts = sred[0][lr] + sred[1][lr] + sred[2][lr] + sred[3][lr];
        float tq = qred[0][lr] + qred[1][lr] + qred[2][lr] + qred[3][lr];
        float mu = ts * (1.f / 512.f);
        float var = tq * (1.f / 512.f) - mu * mu;
        float rs = rsqrtf(var + 1e-6f);
        int row = m0 + lr;
        #pragma unroll
        for (int j = 0; j < 8; j++) {
            int col = wc + j * 16 + mi;
            float o = (acc[j][r] - mu) * rs * lng[col] + lnb[col];
            outH[(size_t)row * 512 + col] = (_Float16)o;
        }
    }
}

// -------- monolithic MFMA flash attention, 8 waves = 2 key-streams x 4 ------
template<bool CAUSAL>
__global__ __launch_bounds__(512)
void attn_mono(const _Float16* __restrict__ Qh, const _Float16* __restrict__ Kh,
               const _Float16* __restrict__ VT, int ldv,
               _Float16* __restrict__ O) {
    const int x = blockIdx.x, bh = blockIdx.y;
    int qt;
    if (CAUSAL) {
        int half = x >> 1;
        int pick = (x & 1) ^ ((bh >> 3) & 1);
        qt = pick ? half : 31 - half;
    } else {
        qt = x;
    }
    const int nt = CAUSAL ? (qt + 1) : 32;
    const int np = (nt + 1) >> 1;          // lockstep iterations (both streams)
    __shared__ _Float16 Qs[64 * 64];
    __shared__ _Float16 Ps[2][64 * 64];    // per-stream P buffer
    __shared__ _Float16 Ks[2][64 * 64];    // per-stream K tile (single-buffered)
    __shared__ _Float16 Vs[2][64 * 64];
    __shared__ float Lsh[64];
    const int tid = threadIdx.x, w = tid >> 6, lane = tid & 63;
    const int w4 = w & 3, st = w >> 2;
    const int mi = lane & 15, qd = lane >> 4;
    const int qbase = qt * 64;
    const int b = bh >> 3, h = bh & 7;
    const _Float16* Qp = Qh + ((size_t)bh * SEQ + qbase) * 64;
    const _Float16* Kp = Kh + (size_t)bh * SEQ * 64;
    const _Float16* Vp = VT + (size_t)(h * 64) * ldv + (size_t)b * SEQ;
    const int lrow = lane >> 3;
    const int gblk = (lane & 7) ^ ((lane >> 3) & 7);
    const int f0 = (qd ^ (mi & 7)) * 8;
    const int f1 = ((qd + 4) ^ (mi & 7)) * 8;

    { // Q staging: 512 threads, one row-segment each
        int r0 = tid >> 3, blk = tid & 7;
        int sw = (blk ^ (r0 & 7)) * 8;
        half8 q0 = *(const half8*)(Qp + r0 * 64 + blk * 8);
        *(half8*)&Qs[r0 * 64 + sw] = q0;
    }
    __syncthreads();
    half8 qb0 = *(half8*)&Qs[(w4 * 16 + mi) * 64 + f0];
    half8 qb1 = *(half8*)&Qs[(w4 * 16 + mi) * 64 + f1];
    f32x4 oacc[4] = {};
    float lacc = 0.f;
    _Float16* Pst = Ps[st];

    for (int i = 0; i < np; i++) {
        const int t = 2 * i + st;
        const bool act = t < nt;           // uniform within a stream
        __syncthreads();                   // own-region LDS free for restage
        if (act) {
            #pragma unroll
            for (int l = 0; l < 2; l++) {
                int cc = l * 4 + w4;
                int row = cc * 8 + lrow;
                __builtin_amdgcn_global_load_lds(
                    (const AS1 unsigned int*)(Kp + ((size_t)(t * 64 + row)) * 64 + gblk * 8),
                    (AS3 unsigned int*)&Ks[st][cc * 512], 16, 0, 0);
                __builtin_amdgcn_global_load_lds(
                    (const AS1 unsigned int*)(Vp + (size_t)row * ldv + t * 64 + gblk * 8),
                    (AS3 unsigned int*)&Vs[st][cc * 512], 16, 0, 0);
            }
        }
        __builtin_amdgcn_s_waitcnt(0x0F70);
        __syncthreads();                   // staged tile visible to stream
        if (!act) continue;                // barrier counts stay uniform
        const _Float16* ksb = Ks[st];
        const _Float16* vsb = Vs[st];
        f32x4 s[4];
        #pragma unroll
        for (int j = 0; j < 4; j++) {
            half8 ka0 = *(const half8*)&ksb[(j * 16 + mi) * 64 + f0];
            half8 ka1 = *(const half8*)&ksb[(j * 16 + mi) * 64 + f1];
            f32x4 a = {};
            a = __builtin_amdgcn_mfma_f32_16x16x32_f16(ka0, qb0, a, 0, 0, 0);
            a = __builtin_amdgcn_mfma_f32_16x16x32_f16(ka1, qb1, a, 0, 0, 0);
            s[j] = a;
        }
        if (CAUSAL && t == qt) {
            int qg = qbase + w4 * 16 + mi;
            #pragma unroll
            for (int j = 0; j < 4; j++)
                #pragma unroll
                for (int r = 0; r < 4; r++) {
                    int key = t * 64 + j * 16 + qd * 4 + r;
                    if (key > qg) s[j][r] = -1e30f;
                }
        }
        #pragma unroll
        for (int j = 0; j < 4; j++)
            #pragma unroll
            for (int r = 0; r < 4; r++) {
                float pv = __builtin_amdgcn_exp2f(s[j][r]);
                s[j][r] = pv;
                lacc += pv;
            }
        #pragma unroll
        for (int j = 0; j < 4; j++) {
            fp16x2 lo = __builtin_amdgcn_cvt_pkrtz(s[j][0], s[j][1]);
            fp16x2 hi = __builtin_amdgcn_cvt_pkrtz(s[j][2], s[j][3]);
            half2_t lo2 = __builtin_bit_cast(half2_t, lo);
            half2_t hi2 = __builtin_bit_cast(half2_t, hi);
            half4 pq;
            pq[0] = lo2[0]; pq[1] = lo2[1]; pq[2] = hi2[0]; pq[3] = hi2[1];
            int blkp = (2 * j + (qd >> 1)) ^ (mi & 7);
            *(half4*)&Pst[(w4 * 16 + mi) * 64 + blkp * 8 + (qd & 1) * 4] = pq;
        }
        half8 pa0 = *(half8*)&Pst[(w4 * 16 + mi) * 64 + f0];
        half8 pa1 = *(half8*)&Pst[(w4 * 16 + mi) * 64 + f1];
        #pragma unroll
        for (int j = 0; j < 4; j++) {
            half8 vb0 = *(const half8*)&vsb[(j * 16 + mi) * 64 + f0];
            half8 vb1 = *(const half8*)&vsb[(j * 16 + mi) * 64 + f1];
            oacc[j] = __builtin_amdgcn_mfma_f32_16x16x32_f16(pa0, vb0, oacc[j], 0, 0, 0);
            oacc[j] = __builtin_amdgcn_mfma_f32_16x16x32_f16(pa1, vb1, oacc[j], 0, 0, 0);
        }
    }
    __syncthreads();                       // all compute done; K/V reusable
    if (st == 1) {                         // dump stream-1 partials
        float* obuf = (float*)Ks;          // 16 KB = 4 waves x 64 x 16 f32
        float* lbuf = (float*)Vs;
        int base = (w4 * 64 + lane) * 16;
        #pragma unroll
        for (int j = 0; j < 4; j++)
            #pragma unroll
            for (int r = 0; r < 4; r++)
                obuf[base + j * 4 + r] = oacc[j][r];
        lbuf[w4 * 64 + lane] = lacc;
    }
    __syncthreads();
    if (st == 0) {                         // merge + L reduce
        const float* obuf = (const float*)Ks;
        const float* lbuf = (const float*)Vs;
        int base = (w4 * 64 + lane) * 16;
        #pragma unroll
        for (int j = 0; j < 4; j++)
            #pragma unroll
            for (int r = 0; r < 4; r++)
                oacc[j][r] += obuf[base + j * 4 + r];
        lacc += lbuf[w4 * 64 + lane];
        lacc += __shfl_xor(lacc, 16, 64);
        lacc += __shfl_xor(lacc, 32, 64);
        if (qd == 0) Lsh[w4 * 16 + mi] = lacc;
    }
    __syncthreads();
    if (st == 0) {
        #pragma unroll
        for (int r = 0; r < 4; r++) {
            float rl = 1.f / Lsh[w4 * 16 + qd * 4 + r];
            int qrow = qbase + w4 * 16 + qd * 4 + r;
            size_t obase = ((size_t)(b * SEQ + qrow)) * 512 + h * 64;
            #pragma unroll
            for (int j = 0; j < 4; j++)
                O[obase + j * 16 + mi] = (_Float16)(oacc[j][r] * rl);
        }
    }
}

// ---- residual add (f16) + f16 split-K partials + LayerNorm (final ln3) ----
template<typename RT>
__global__ __launch_bounds__(256)
void add_ln(const RT* __restrict__ res, const _Float16* __restrict__ y,
            size_t pstride, int nparts,
            const float* __restrict__ g, const float* __restrict__ bb,
            float* __restrict__ outF, _Float16* __restrict__ outH) {
    int row = blockIdx.x;
    int tid = threadIdx.x;
    size_t base = (size_t)row * 512;
    float x0 = (float)res[base + tid];
    float x1 = (float)res[base + tid + 256];
    for (int s = 0; s < nparts; s++) {
        x0 += (float)y[s * pstride + base + tid];
        x1 += (float)y[s * pstride + base + tid + 256];
    }
    float s = x0 + x1, sq = x0 * x0 + x1 * x1;
    #pragma unroll
    for (int off = 32; off > 0; off >>= 1) {
        s += __shfl_xor(s, off, 64);
        sq += __shfl_xor(sq, off, 64);
    }
    __shared__ float ls[4], lq[4];
    int w = tid >> 6;
    if ((tid & 63) == 0) { ls[w] = s; lq[w] = sq; }
    __syncthreads();
    s = ls[0] + ls[1] + ls[2] + ls[3];
    sq = lq[0] + lq[1] + lq[2] + lq[3];
    float mu = s * (1.f / 512.f);
    float var = sq * (1.f / 512.f) - mu * mu;
    float rs = rsqrtf(var + 1e-6f);
    float o0 = (x0 - mu) * rs * g[tid] + bb[tid];
    float o1 = (x1 - mu) * rs * g[tid + 256] + bb[tid + 256];
    if (outF) { outF[base + tid] = o0; outF[base + tid + 256] = o1; }
    if (outH) { outH[base + tid] = (_Float16)o0; outH[base + tid + 256] = (_Float16)o1; }
}

extern "C" void kernel_launch(void* const* d_in, const int* in_sizes, int n_in,
                              void* d_out, int out_size, void* d_ws, size_t ws_size,
                              hipStream_t stream) {
    (void)in_sizes; (void)n_in; (void)out_size; (void)ws_size;
    const float* inp  = (const float*)d_in[0];
    const float* enc  = (const float*)d_in[1];
    const float* q1_w = (const float*)d_in[4];
    const float* q1_b = (const float*)d_in[5];
    const float* k1_w = (const float*)d_in[6];
    const float* k1_b = (const float*)d_in[7];
    const float* v1_w = (const float*)d_in[8];
    const float* v1_b = (const float*)d_in[9];
    const float* o1_w = (const float*)d_in[10];
    const float* o1_b = (const float*)d_in[11];
    const float* q2_w = (const float*)d_in[12];
    const float* q2_b = (const float*)d_in[13];
    const float* k2_w = (const float*)d_in[14];
    const float* k2_b = (const float*)d_in[15];
    const float* v2_w = (const float*)d_in[16];
    const float* v2_b = (const float*)d_in[17];
    const float* o2_w = (const float*)d_in[18];
    const float* o2_b = (const float*)d_in[19];
    const float* f1_w = (const float*)d_in[20];
    const float* f1_b = (const float*)d_in[21];
    const float* f2_w = (const float*)d_in[22];
    const float* f2_b = (const float*)d_in[23];
    const float* ln1_g = (const float*)d_in[24];
    const float* ln1_b = (const float*)d_in[25];
    const float* ln2_g = (const float*)d_in[26];
    const float* ln2_b = (const float*)d_in[27];
    const float* ln3_g = (const float*)d_in[28];
    const float* ln3_b = (const float*)d_in[29];

    char* p = (char*)d_ws;
    auto alloc = [&](size_t bytes) { char* r = p; p += (bytes + 255) & ~(size_t)255; return (void*)r; };
    _Float16* xh    = (_Float16*)alloc((size_t)M * DM * 2);
    _Float16* eh    = (_Float16*)alloc((size_t)M * DM * 2);
    _Float16* qk1t  = (_Float16*)alloc((size_t)1024 * DM * 2);
    _Float16* v1t   = (_Float16*)alloc((size_t)DM * DM * 2);
    _Float16* o1t   = (_Float16*)alloc((size_t)DM * DM * 2);
    _Float16* qk2t  = (_Float16*)alloc((size_t)1024 * DM * 2);
    _Float16* v2t   = (_Float16*)alloc((size_t)DM * DM * 2);
    _Float16* o2t   = (_Float16*)alloc((size_t)DM * DM * 2);
    _Float16* f1t   = (_Float16*)alloc((size_t)FFD * DM * 2);
    _Float16* f2t   = (_Float16*)alloc((size_t)DM * FFD * 2);
    float* qk1b     = (float*)alloc(1024 * 4);
    float* qk2b     = (float*)alloc(1024 * 4);
    _Float16* Qh1   = (_Float16*)alloc((size_t)M * DM * 2);
    _Float16* Kh1   = (_Float16*)alloc((size_t)M * DM * 2);
    _Float16* Qh2   = (_Float16*)alloc((size_t)M * DM * 2);
    _Float16* Kh2   = (_Float16*)alloc((size_t)M * DM * 2);
    _Float16* V1T   = (_Float16*)alloc((size_t)DM * M * 2);
    _Float16* V2T   = (_Float16*)alloc((size_t)DM * M * 2);
    _Float16* Ah    = (_Float16*)alloc((size_t)M * DM * 2);
    _Float16* Ph    = (_Float16*)alloc((size_t)2 * M * DM * 2);   // f16 split-K partials
    _Float16* out1h = (_Float16*)alloc((size_t)M * DM * 2);
    _Float16* out2h = (_Float16*)alloc((size_t)M * DM * 2);
    _Float16* hh    = (_Float16*)alloc((size_t)M * FFD * 2);
    const size_t PS = (size_t)M * DM;   // split-K partial stride (elements)

    dim3 t256(256), t512(512);
    // 1) all preprocessing in one launch
    preproc<<<dim3(1026 + 2048), t256, 0, stream>>>(
        q1_w, k1_w, v1_w, o1_w, q2_w, k2_w, v2_w, o2_w, f1_w, f2_w,
        qk1t, v1t, o1t, qk2t, v2t, o2t, f1t, f2t,
        q1_b, k1_b, q2_b, k2_b, qk1b, qk2b, inp, enc, xh, eh);

    // 2) QK projections (both) + V1^T in ONE launch: 1280 blocks (5/CU)
    qkv_gemm<<<dim3(1280), t256, 0, stream>>>(
        xh, eh, qk1t, qk2t, qk1b, qk2b, Qh1, Kh1, Qh2, Kh2, v1t, v1_b, V1T);

    // 3) self attention (causal, 8-wave dual-stream, CU-pair balanced)
    attn_mono<true><<<dim3(32, 16), t512, 0, stream>>>(Qh1, Kh1, V1T, M, Ah);
    // 4) O1-projection + residual(inp f32) + LN1 -> out1h  (fused, 256 blocks)
    oproj_ln<float><<<dim3(256), t256, 0, stream>>>(
        Ah, o1t, o1_b, inp, ln1_g, ln1_b, out1h);

    // 5) V2^T = v2_w^T . out1^T
    gemm_tn<64, 64, 32, 32, false, 3, 1><<<dim3(64, 8), t256, 0, stream>>>(
        v2t, out1h, v2_b, nullptr, V2T, 512, M, 512);
    // 6) cross attention
    attn_mono<false><<<dim3(32, 16), t512, 0, stream>>>(Qh2, Kh2, V2T, M, Ah);
    // 7) O2-projection + residual(out1h f16) + LN2 -> out2h  (fused, 256 blocks)
    oproj_ln<_Float16><<<dim3(256), t256, 0, stream>>>(
        Ah, o2t, o2_b, out1h, ln2_g, ln2_b, out2h);

    // 8) FFN1
    gemm_tn<128, 64, 64, 32, true, 0, 1><<<dim3(32, 32), t256, 0, stream>>>(
        out2h, f1t, f1_b, nullptr, hh, M, 2048, 512);
    // 9) FFN2 split-K -> Ph[0..1]
    gemm_tn<64, 64, 32, 32, false, 5, 2><<<dim3(8, 64, 2), t256, 0, stream>>>(
        hh, f2t, f2_b, nullptr, Ph, M, 512, 2048);
    // 10) final residual + LN3 -> d_out
    add_ln<_Float16><<<dim3(M), t256, 0, stream>>>(out2h, Ph, PS, 2, ln3_g, ln3_b, (float*)d_out, nullptr);
}